// Round 11
// baseline (5076.440 us; speedup 1.0000x reference)
//
#include <hip/hip_runtime.h>
#include <hip/hip_bf16.h>
#include <stdint.h>
#include <stddef.h>

#define SEQ   512
#define BATCH 64
#define NIN   1024
#define NHID  1024
#define NG    4096   // 4*NHID

typedef __attribute__((ext_vector_type(8))) short bf16x8;
typedef __attribute__((ext_vector_type(4))) float f32x4;
typedef __attribute__((ext_vector_type(4))) uint32_t u32x4;

static __device__ __forceinline__ ushort f2bf(float f) {
  uint32_t u = __builtin_bit_cast(uint32_t, f);
  uint32_t lsb = (u >> 16) & 1u;
  u += 0x7fffu + lsb;           // round-to-nearest-even
  return (ushort)(u >> 16);
}

static __device__ __forceinline__ f32x4 mfma_bf16(bf16x8 a, bf16x8 b, f32x4 c) {
  return __builtin_amdgcn_mfma_f32_16x16x32_bf16(a, b, c, 0, 0, 0);
}

static __device__ __forceinline__ void lds_load16(const ushort* g, ushort* l) {
  __builtin_amdgcn_global_load_lds(
      (const __attribute__((address_space(1))) void*)g,
      (__attribute__((address_space(3))) void*)l, 16, 0, 0);
}

// ---- exchange primitives: DEVICE scope (sc1) -- proven correct in r10 ----
static __device__ __forceinline__ void st_short_dev(ushort* p, uint32_t v) {
  asm volatile("global_store_short %0, %1, off sc1" :: "v"(p), "v"(v) : "memory");
}
static __device__ __forceinline__ void st_dword_dev(uint32_t* p, uint32_t v) {
  asm volatile("global_store_dword %0, %1, off sc1" :: "v"(p), "v"(v) : "memory");
}
static __device__ __forceinline__ uint32_t ld_dword_dev(const uint32_t* p) {
  uint32_t v;
  asm volatile("global_load_dword %0, %1, off sc1" : "=v"(v) : "v"(p) : "memory");
  return v;
}
static __device__ __forceinline__ u32x4 ld_x4_dev(const ushort* p) {
  u32x4 v;
  asm volatile("global_load_dwordx4 %0, %1, off sc1" : "=v"(v) : "v"(p) : "memory");
  return v;
}

#define WAITV(n) do { asm volatile("s_waitcnt vmcnt(" #n ")" ::: "memory"); \
                      __builtin_amdgcn_sched_barrier(0); } while (0)

// fast transcendentals
static __device__ __forceinline__ float sigm_f(float x) {
  return __builtin_amdgcn_rcpf(1.f + __expf(-x));
}
static __device__ __forceinline__ float tanh_f(float x) {
  return 1.f - 2.f * __builtin_amdgcn_rcpf(__expf(2.f * x) + 1.f);
}

// ---------------- converts ----------------

__global__ __launch_bounds__(256) void k_convert_x(const float* __restrict__ X,
                                                   ushort* __restrict__ Xb, int n4) {
  int i = blockIdx.x * 256 + threadIdx.x;
  if (i < n4) {
    float4 v = ((const float4*)X)[i];
    ushort4 o;
    o.x = f2bf(v.x); o.y = f2bf(v.y); o.z = f2bf(v.z); o.w = f2bf(v.w);
    ((ushort4*)Xb)[i] = o;
  }
}

// permuted row order: p = cg*64 + g*16 + j  <->  r = g*1024 + cg*16 + j
__global__ __launch_bounds__(256) void k_convert_w(const float* __restrict__ W,
                                                   const float* __restrict__ bvec,
                                                   ushort* __restrict__ Wxb,
                                                   ushort* __restrict__ Whb,
                                                   float* __restrict__ bp) {
  int p = blockIdx.x;
  int cg = p >> 6, g = (p >> 4) & 3, j = p & 15;
  int r = g * 1024 + cg * 16 + j;
  const float* src = W + (size_t)r * 2048;
  for (int k4 = threadIdx.x; k4 < 512; k4 += 256) {
    float4 v = ((const float4*)src)[k4];
    ushort4 o;
    o.x = f2bf(v.x); o.y = f2bf(v.y); o.z = f2bf(v.z); o.w = f2bf(v.w);
    if (k4 < 256) ((ushort4*)(Wxb + (size_t)p * 1024))[k4] = o;
    else          ((ushort4*)(Whb + (size_t)p * 1024))[k4 - 256] = o;
  }
  if (threadIdx.x == 0) bp[p] = bvec[r];
}

// zero h ping-pong (device-scope stores to match readers), c-state, flags
__global__ __launch_bounds__(256) void k_zero(ushort* __restrict__ hb0,
                                              ushort* __restrict__ hb1,
                                              float* __restrict__ cst,
                                              uint32_t* __restrict__ flg) {
  int i = blockIdx.x * 256 + threadIdx.x;  // 65536 total
  st_short_dev(hb0 + i, 0u);
  st_short_dev(hb1 + i, 0u);
  cst[i] = 0.f;
  if (blockIdx.x == 0) st_dword_dev(flg + threadIdx.x, 0u);
}

// ---------------- GEMM1 chunk (unchanged, proven) ----------------

__global__ __launch_bounds__(256) void k_gemm1(const ushort* __restrict__ Xbc,
                                               const ushort* __restrict__ Wxb,
                                               const float* __restrict__ bp,
                                               float* __restrict__ Axc) {
  __shared__ ushort As[128 * 32];
  __shared__ ushort Bs[128 * 32];
  const int m0 = blockIdx.x * 128;
  const int n0 = blockIdx.y * 128;
  const int tid = threadIdx.x;
  const int w = tid >> 6, l = tid & 63;
  const int wr = w >> 1, wc = w & 1;
  const int lr = l >> 2;
  const int lc = (l & 3) * 8;
  const int fr = l & 15, fk8 = (l >> 4) * 8, fq = l >> 4;

  f32x4 acc[4][4] = {};

  for (int kb = 0; kb < 1024; kb += 32) {
    lds_load16(Xbc + (size_t)(m0 + w * 16 + lr) * 1024 + kb + lc,       &As[w * 512]);
    lds_load16(Xbc + (size_t)(m0 + (w + 4) * 16 + lr) * 1024 + kb + lc, &As[(w + 4) * 512]);
    lds_load16(Wxb + (size_t)(n0 + w * 16 + lr) * 1024 + kb + lc,       &Bs[w * 512]);
    lds_load16(Wxb + (size_t)(n0 + (w + 4) * 16 + lr) * 1024 + kb + lc, &Bs[(w + 4) * 512]);
    __syncthreads();
    bf16x8 af[4], bfr[4];
#pragma unroll
    for (int i = 0; i < 4; i++) af[i]  = *(const bf16x8*)&As[(wr * 64 + i * 16 + fr) * 32 + fk8];
#pragma unroll
    for (int i = 0; i < 4; i++) bfr[i] = *(const bf16x8*)&Bs[(wc * 64 + i * 16 + fr) * 32 + fk8];
#pragma unroll
    for (int i = 0; i < 4; i++)
#pragma unroll
      for (int jj = 0; jj < 4; jj++)
        acc[i][jj] = mfma_bf16(af[i], bfr[jj], acc[i][jj]);
    __syncthreads();
  }

#pragma unroll
  for (int jj = 0; jj < 4; jj++) {
    int gc = n0 + wc * 64 + jj * 16 + fr;
    float bb = bp[gc];
#pragma unroll
    for (int i = 0; i < 4; i++) {
      int grb = m0 + wr * 64 + i * 16 + fq * 4;
#pragma unroll
      for (int jr = 0; jr < 4; jr++)
        Axc[(size_t)(grb + jr) * NG + gc] = acc[i][jj][jr] + bb;
    }
  }
}

// ---------------- persistent recurrence chunk: wave-independent workers ----------------
// grid 64 blocks x 4 waves. Block hg owns gate cols [hg*64,+64) (= h-cols
// [hg*16,+16)); its 128KB Wh slice is staged ONCE into LDS in FRAGMENT-MAJOR
// layout (conflict-free stride-1 reads). Wave w = independent worker for team
// w (batches [w*16,+16)), full K=1024 (128 MFMA/step), no K-split:
//   - NO __syncthreads in the step loop (waves fully decoupled)
//   - NO LDS reduce: MFMA C layout puts i,f,o,g for (batch,hcol) in one lane
//     (acc[bj=gate][jr]); epilogue lane-local; c-state in creg[4]
//   - publish: wave-level vmcnt(0) covers all 64 lanes' h stores (VMEM
//     instructions are per-wave), then lane0 stores flag[team*64+hg] = t+1
//   - consume: lane l polls flag[team*64+l] >= t, then 32x16B h burst with
//     8-deep rolling vmcnt(8) load/MFMA pipeline
// Exchange scope: sc1 (device) -- proven correct in r10. Overwrite safety as
// r7: buf written at t was last read as h_{t-2}; all team flags >= t implies
// those reads completed.

#define MFG(arr, ks0) do {                                                    \
    _Pragma("unroll")                                                         \
    for (int ks = 0; ks < 8; ++ks) {                                          \
      bf16x8 a_ = __builtin_bit_cast(bf16x8, arr[ks]);                        \
      _Pragma("unroll")                                                       \
      for (int bj = 0; bj < 4; ++bj) {                                        \
        bf16x8 b_ = *(const bf16x8*)&Wlds[(size_t)(((bj * 32) + (ks0) + ks) * 64 + l) * 8]; \
        acc[bj] = mfma_bf16(a_, b_, acc[bj]);                                 \
      }                                                                       \
    }                                                                         \
  } while (0)

__global__ __launch_bounds__(256) void k_persist(const ushort* __restrict__ Whb,
                                                 const float* __restrict__ Axc,
                                                 ushort* __restrict__ hb0,
                                                 ushort* __restrict__ hb1,
                                                 float* __restrict__ out,
                                                 uint32_t* __restrict__ flags,
                                                 float* __restrict__ cst,
                                                 int t0, int TC) {
  __shared__ ushort Wlds[4 * 32 * 64 * 8];   // 128 KB, fragment-major

  const int hg = blockIdx.x;                  // 0..63: gate-col group
  const int tid = threadIdx.x;
  const int team = tid >> 6;                  // wave index == team
  const int l = tid & 63, fr = l & 15, fq = l >> 4;

  // ---- stage Wh slice, fragment-major: frag f = (bj*32+ks)*64 + lane ----
  for (int it = 0; it < 32; ++it) {
    int f = it * 256 + tid;
    int fl = f & 63, ks = (f >> 6) & 31, bj = f >> 11;
    bf16x8 v = *(const bf16x8*)(Whb + (size_t)(hg * 64 + bj * 16 + (fl & 15)) * 1024
                                + ks * 32 + (fl >> 4) * 8);
    *(bf16x8*)&Wlds[(size_t)f * 8] = v;
  }
  __syncthreads();   // the ONLY block barrier; loop below is barrier-free

  const int r0 = fq * 4;                      // lane's 4 batch rows (in-team)
  // c-state + self h index base: batch row (team*16 + r0 + jr), col hg*16+fr
  const int selfbase = (team * 16 + r0) * 1024 + hg * 16 + fr;
  float creg[4];
#pragma unroll
  for (int jr = 0; jr < 4; ++jr) creg[jr] = cst[selfbase + jr * 1024];

  const size_t hoff = (size_t)(team * 16 + fr) * 1024 + fq * 8;  // h read base
  const uint32_t* fladdr = flags + team * 64 + l;                // poll target

  for (int tt = 0; tt < TC; ++tt) {
    const int t = t0 + tt;
    const ushort* hb_r = (t & 1) ? hb0 : hb1;   // h_{t-1} in buf[(t-1)&1]
    ushort*       hb_w = (t & 1) ? hb1 : hb0;   // h_t -> buf[t&1]

    // ---- Ax prefetch (h-independent; in flight during the poll) ----
    const float* axp = Axc + ((size_t)tt * 64 + team * 16 + r0) * NG + hg * 64;
    float ax[4][4];
#pragma unroll
    for (int bj = 0; bj < 4; ++bj)
#pragma unroll
      for (int jr = 0; jr < 4; ++jr)
        ax[bj][jr] = axp[(size_t)jr * NG + bj * 16 + fr];

    // ---- poll 64 team flags (1/lane) until all >= t ----
    if (t > 0) {
      int guard = 0;
      while (true) {
        uint32_t v = ld_dword_dev(fladdr);
        WAITV(0);
        if (__all((int)(v >= (uint32_t)t))) break;
        if (++guard > (1 << 15)) break;   // bug guard: fail visibly, don't hang
      }
    }

    // ---- h burst (32 x 16B) + rolling 8-deep vmcnt pipeline, 128 MFMA ----
    const ushort* aBt = hb_r + hoff;
    u32x4 hvA[8], hvB[8];
    f32x4 acc[4] = {};
#pragma unroll
    for (int ks = 0; ks < 8; ++ks) hvA[ks] = ld_x4_dev(aBt + ks * 32);
#pragma unroll
    for (int ks = 0; ks < 8; ++ks) hvB[ks] = ld_x4_dev(aBt + (8 + ks) * 32);
    WAITV(8);  MFG(hvA, 0);
#pragma unroll
    for (int ks = 0; ks < 8; ++ks) hvA[ks] = ld_x4_dev(aBt + (16 + ks) * 32);
    WAITV(8);  MFG(hvB, 8);
#pragma unroll
    for (int ks = 0; ks < 8; ++ks) hvB[ks] = ld_x4_dev(aBt + (24 + ks) * 32);
    WAITV(8);  MFG(hvA, 16);
    WAITV(0);  MFG(hvB, 24);

    // ---- lane-local epilogue: 4 (batch,hcol) pairs, gates bj=0..3 ----
#pragma unroll
    for (int jr = 0; jr < 4; ++jr) {
      float ai = acc[0][jr] + ax[0][jr];
      float af = acc[1][jr] + ax[1][jr];
      float ao = acc[2][jr] + ax[2][jr];
      float ag = acc[3][jr] + ax[3][jr];
      float ig = sigm_f(ai);
      float fg = sigm_f(af);
      float og = sigm_f(ao);
      float gg = tanh_f(ag);
      creg[jr] = creg[jr] * fg + ig * gg;
      float h = og * tanh_f(creg[jr]);
      int hidx = selfbase + jr * 1024;
      st_short_dev(hb_w + hidx, (uint32_t)f2bf(h));
      out[(size_t)t * 65536 + hidx] = h;
      if (t == SEQ - 1) out[(size_t)SEQ * 65536 + hidx] = h;
    }

    // ---- publish: one wave-level drain covers all lanes, then flag ----
    asm volatile("s_waitcnt vmcnt(0)" ::: "memory");
    __builtin_amdgcn_sched_barrier(0);
    if (l == 0) st_dword_dev(flags + team * 64 + hg, (uint32_t)(t + 1));
  }

#pragma unroll
  for (int jr = 0; jr < 4; ++jr) cst[selfbase + jr * 1024] = creg[jr];
}

// ---------------- fallback per-step kernel (ws too small for any Ax chunk) ----------------

__global__ __launch_bounds__(256) void k_step(int t,
                                              const ushort* __restrict__ Xb,
                                              const ushort* __restrict__ Wxb,
                                              const ushort* __restrict__ Whb,
                                              const float* __restrict__ bp,
                                              const ushort* __restrict__ hprev,
                                              ushort* __restrict__ hnext,
                                              float* __restrict__ cst,
                                              float* __restrict__ out) {
  __shared__ float red[4][16][65];
  const int bidx = blockIdx.x;
  const int cg = bidx & 63, mb = bidx >> 6;
  const int b0 = mb * 16, pcol = cg * 64;
  const int tid = threadIdx.x, w = tid >> 6, l = tid & 63;
  const int fr = l & 15, fk8 = (l >> 4) * 8, fq = l >> 4;

  f32x4 acc[4] = {};

  const ushort* aSrc;
  const ushort* bMat;
  int kbase;
  if (w < 2) { aSrc = Xb + (size_t)(t * 64 + b0 + fr) * 1024 + w * 512 + fk8; bMat = Wxb; kbase = w * 512; }
  else       { aSrc = hprev + (size_t)(b0 + fr) * 1024 + (w - 2) * 512 + fk8; bMat = Whb; kbase = (w - 2) * 512; }
  const ushort* bRow = bMat + (size_t)(pcol + fr) * 1024 + kbase + fk8;

#pragma unroll
  for (int ks = 0; ks < 16; ks++) {
    int kk = ks * 32;
    bf16x8 a = *(const bf16x8*)(aSrc + kk);
#pragma unroll
    for (int bj = 0; bj < 4; bj++) {
      bf16x8 bfv = *(const bf16x8*)(bRow + (size_t)bj * 16 * 1024 + kk);
      acc[bj] = mfma_bf16(a, bfv, acc[bj]);
    }
  }

#pragma unroll
  for (int bj = 0; bj < 4; bj++)
#pragma unroll
    for (int jr = 0; jr < 4; jr++)
      red[w][fq * 4 + jr][bj * 16 + fr] = acc[bj][jr];
  __syncthreads();

  const int b = tid >> 4, j = tid & 15;
  float ai_ = 0.f, af_ = 0.f, ao_ = 0.f, ag_ = 0.f;
#pragma unroll
  for (int ww = 0; ww < 4; ww++) {
    ai_ += red[ww][b][j];
    af_ += red[ww][b][16 + j];
    ao_ += red[ww][b][32 + j];
    ag_ += red[ww][b][48 + j];
  }
  ai_ += bp[pcol + j]; af_ += bp[pcol + 16 + j]; ao_ += bp[pcol + 32 + j]; ag_ += bp[pcol + 48 + j];

  float ig = sigm_f(ai_);
  float fg = sigm_f(af_);
  float og = sigm_f(ao_);
  float gg = tanh_f(ag_);
  int hidx = (b0 + b) * 1024 + cg * 16 + j;
  float cn = cst[hidx] * fg + ig * gg;
  cst[hidx] = cn;
  float h = og * tanh_f(cn);
  out[(size_t)t * 65536 + hidx] = h;
  hnext[hidx] = f2bf(h);
  if (t == SEQ - 1) out[(size_t)SEQ * 65536 + hidx] = h;
}

// ---------------- host ----------------

extern "C" void kernel_launch(void* const* d_in, const int* in_sizes, int n_in,
                              void* d_out, int out_size, void* d_ws, size_t ws_size,
                              hipStream_t stream) {
  const float* X    = (const float*)d_in[0];
  const float* W    = (const float*)d_in[1];
  const float* bvec = (const float*)d_in[2];
  float* out = (float*)d_out;
  char* ws = (char*)d_ws;

  size_t off = 0;
  auto alloc = [&](size_t bytes) -> char* {
    char* p = ws + off;
    off += (bytes + 255) & ~(size_t)255;
    return p;
  };
  ushort*   Xb  = (ushort*)alloc((size_t)SEQ * BATCH * NIN * 2);
  ushort*   Wxb = (ushort*)alloc((size_t)NG * NIN * 2);
  ushort*   Whb = (ushort*)alloc((size_t)NG * NHID * 2);
  float*    bp  = (float*)alloc((size_t)NG * 4);
  ushort*   hb0 = (ushort*)alloc((size_t)BATCH * NHID * 2);
  ushort*   hb1 = (ushort*)alloc((size_t)BATCH * NHID * 2);
  float*    cst = (float*)alloc((size_t)BATCH * NHID * 4);
  uint32_t* flg = (uint32_t*)alloc(256 * 4);
  size_t base_need = off;

  if (ws_size < base_need) return;

  // largest chunk length TC (steps) whose f32 Ax chunk fits the remaining ws
  size_t avail = ws_size - base_need;
  int TC = 0;
  for (int tc = 512; tc >= 16; tc >>= 1) {
    if ((size_t)tc * 64 * NG * 4 <= avail) { TC = tc; break; }
  }
  float* Axc = (float*)(ws + base_need);  // base_need is 256B-aligned

  k_convert_x<<<(SEQ * BATCH * NIN / 4 + 255) / 256, 256, 0, stream>>>(X, Xb, SEQ * BATCH * NIN / 4);
  k_convert_w<<<NG, 256, 0, stream>>>(W, bvec, Wxb, Whb, bp);
  k_zero<<<BATCH * NHID / 256, 256, 0, stream>>>(hb0, hb1, cst, flg);

  if (TC > 0) {
    for (int c = 0; c < SEQ / TC; ++c) {
      k_gemm1<<<dim3(TC * 64 / 128, NG / 128), 256, 0, stream>>>(
          Xb + (size_t)c * TC * 64 * 1024, Wxb, bp, Axc);
      k_persist<<<64, 256, 0, stream>>>(Whb, Axc, hb0, hb1, out, flg, cst, c * TC, TC);
    }
  } else {
    for (int t = 0; t < SEQ; t++) {
      const ushort* hp = (t & 1) ? hb1 : hb0;
      ushort*       hn = (t & 1) ? hb0 : hb1;
      k_step<<<256, 256, 0, stream>>>(t, Xb, Wxb, Whb, bp, hp, hn, cst, out);
    }
  }
}

// Round 12
// 2296.376 us; speedup vs baseline: 2.2106x; 2.2106x over previous
//
#include <hip/hip_runtime.h>
#include <hip/hip_bf16.h>
#include <stdint.h>
#include <stddef.h>

#define SEQ   512
#define BATCH 64
#define NIN   1024
#define NHID  1024
#define NG    4096   // 4*NHID

typedef __attribute__((ext_vector_type(8))) short bf16x8;
typedef __attribute__((ext_vector_type(4))) float f32x4;
typedef __attribute__((ext_vector_type(4))) uint32_t u32x4;

static __device__ __forceinline__ ushort f2bf(float f) {
  uint32_t u = __builtin_bit_cast(uint32_t, f);
  uint32_t lsb = (u >> 16) & 1u;
  u += 0x7fffu + lsb;           // round-to-nearest-even
  return (ushort)(u >> 16);
}

static __device__ __forceinline__ f32x4 mfma_bf16(bf16x8 a, bf16x8 b, f32x4 c) {
  return __builtin_amdgcn_mfma_f32_16x16x32_bf16(a, b, c, 0, 0, 0);
}

static __device__ __forceinline__ void lds_load16(const ushort* g, ushort* l) {
  __builtin_amdgcn_global_load_lds(
      (const __attribute__((address_space(1))) void*)g,
      (__attribute__((address_space(3))) void*)l, 16, 0, 0);
}

// ---- exchange primitives: DEVICE scope (sc1) -- proven correct in r10 ----
static __device__ __forceinline__ void st_short_dev(ushort* p, uint32_t v) {
  asm volatile("global_store_short %0, %1, off sc1" :: "v"(p), "v"(v) : "memory");
}
static __device__ __forceinline__ void st_dword_dev(uint32_t* p, uint32_t v) {
  asm volatile("global_store_dword %0, %1, off sc1" :: "v"(p), "v"(v) : "memory");
}
static __device__ __forceinline__ void st_x4_dev(ushort* p, u32x4 v) {
  asm volatile("global_store_dwordx4 %0, %1, off sc1" :: "v"(p), "v"(v) : "memory");
}
static __device__ __forceinline__ uint32_t ld_dword_dev(const uint32_t* p) {
  uint32_t v;
  asm volatile("global_load_dword %0, %1, off sc1" : "=v"(v) : "v"(p) : "memory");
  return v;
}
static __device__ __forceinline__ u32x4 ld_x4_dev(const ushort* p) {
  u32x4 v;
  asm volatile("global_load_dwordx4 %0, %1, off sc1" : "=v"(v) : "v"(p) : "memory");
  return v;
}

#define WAITV(n) do { asm volatile("s_waitcnt vmcnt(" #n ")" ::: "memory"); \
                      __builtin_amdgcn_sched_barrier(0); } while (0)

// fast transcendentals
static __device__ __forceinline__ float sigm_f(float x) {
  return __builtin_amdgcn_rcpf(1.f + __expf(-x));
}
static __device__ __forceinline__ float tanh_f(float x) {
  return 1.f - 2.f * __builtin_amdgcn_rcpf(__expf(2.f * x) + 1.f);
}

// ---------------- converts ----------------

__global__ __launch_bounds__(256) void k_convert_x(const float* __restrict__ X,
                                                   ushort* __restrict__ Xb, int n4) {
  int i = blockIdx.x * 256 + threadIdx.x;
  if (i < n4) {
    float4 v = ((const float4*)X)[i];
    ushort4 o;
    o.x = f2bf(v.x); o.y = f2bf(v.y); o.z = f2bf(v.z); o.w = f2bf(v.w);
    ((ushort4*)Xb)[i] = o;
  }
}

// permuted row order: p = cg*64 + g*16 + j  <->  r = g*1024 + cg*16 + j
__global__ __launch_bounds__(256) void k_convert_w(const float* __restrict__ W,
                                                   const float* __restrict__ bvec,
                                                   ushort* __restrict__ Wxb,
                                                   ushort* __restrict__ Whb,
                                                   float* __restrict__ bp) {
  int p = blockIdx.x;
  int cg = p >> 6, g = (p >> 4) & 3, j = p & 15;
  int r = g * 1024 + cg * 16 + j;
  const float* src = W + (size_t)r * 2048;
  for (int k4 = threadIdx.x; k4 < 512; k4 += 256) {
    float4 v = ((const float4*)src)[k4];
    ushort4 o;
    o.x = f2bf(v.x); o.y = f2bf(v.y); o.z = f2bf(v.z); o.w = f2bf(v.w);
    if (k4 < 256) ((ushort4*)(Wxb + (size_t)p * 1024))[k4] = o;
    else          ((ushort4*)(Whb + (size_t)p * 1024))[k4 - 256] = o;
  }
  if (threadIdx.x == 0) bp[p] = bvec[r];
}

// zero h ping-pong, c-state, replicated flags (16384 dwords)
__global__ __launch_bounds__(256) void k_zero(ushort* __restrict__ hb0,
                                              ushort* __restrict__ hb1,
                                              float* __restrict__ cst,
                                              uint32_t* __restrict__ flg2) {
  int i = blockIdx.x * 256 + threadIdx.x;  // 65536 total
  st_short_dev(hb0 + i, 0u);
  st_short_dev(hb1 + i, 0u);
  cst[i] = 0.f;
  if (i < 256 * 64) st_dword_dev(flg2 + i, 0u);
}

// ---------------- GEMM1 chunk (unchanged, proven) ----------------

__global__ __launch_bounds__(256) void k_gemm1(const ushort* __restrict__ Xbc,
                                               const ushort* __restrict__ Wxb,
                                               const float* __restrict__ bp,
                                               float* __restrict__ Axc) {
  __shared__ ushort As[128 * 32];
  __shared__ ushort Bs[128 * 32];
  const int m0 = blockIdx.x * 128;
  const int n0 = blockIdx.y * 128;
  const int tid = threadIdx.x;
  const int w = tid >> 6, l = tid & 63;
  const int wr = w >> 1, wc = w & 1;
  const int lr = l >> 2;
  const int lc = (l & 3) * 8;
  const int fr = l & 15, fk8 = (l >> 4) * 8, fq = l >> 4;

  f32x4 acc[4][4] = {};

  for (int kb = 0; kb < 1024; kb += 32) {
    lds_load16(Xbc + (size_t)(m0 + w * 16 + lr) * 1024 + kb + lc,       &As[w * 512]);
    lds_load16(Xbc + (size_t)(m0 + (w + 4) * 16 + lr) * 1024 + kb + lc, &As[(w + 4) * 512]);
    lds_load16(Wxb + (size_t)(n0 + w * 16 + lr) * 1024 + kb + lc,       &Bs[w * 512]);
    lds_load16(Wxb + (size_t)(n0 + (w + 4) * 16 + lr) * 1024 + kb + lc, &Bs[(w + 4) * 512]);
    __syncthreads();
    bf16x8 af[4], bfr[4];
#pragma unroll
    for (int i = 0; i < 4; i++) af[i]  = *(const bf16x8*)&As[(wr * 64 + i * 16 + fr) * 32 + fk8];
#pragma unroll
    for (int i = 0; i < 4; i++) bfr[i] = *(const bf16x8*)&Bs[(wc * 64 + i * 16 + fr) * 32 + fk8];
#pragma unroll
    for (int i = 0; i < 4; i++)
#pragma unroll
      for (int jj = 0; jj < 4; jj++)
        acc[i][jj] = mfma_bf16(af[i], bfr[jj], acc[i][jj]);
    __syncthreads();
  }

#pragma unroll
  for (int jj = 0; jj < 4; jj++) {
    int gc = n0 + wc * 64 + jj * 16 + fr;
    float bb = bp[gc];
#pragma unroll
    for (int i = 0; i < 4; i++) {
      int grb = m0 + wr * 64 + i * 16 + fq * 4;
#pragma unroll
      for (int jr = 0; jr < 4; jr++)
        Axc[(size_t)(grb + jr) * NG + gc] = acc[i][jj][jr] + bb;
    }
  }
}

// ---------------- persistent recurrence chunk ----------------
// r7 structure: 256 blocks = 4 teams x 64 hg; block = 16 batches x 64 gate
// cols; 4 waves split K. Protocol (proven, sc1 device scope r10): producer h
// stores -> drain -> flag; consumer polls flags then reads h. Anti-contention
// changes vs r7:
//  (1) REPLICATED flags: producer wave0 stores t+1 into each of its 64
//      consumers' PRIVATE flag slots (flg2[consumer_bid*64 + producer_hg]).
//      Consumer polls only its own 64-dword array -> no L3 line hotspot
//      (r7: 256 waves/team hammered the same 4 lines every round).
//  (2) PACKED h publish: epilogue -> LDS tile h_sh[16][16] -> wave0 stores
//      32 x 16B sc1 (vs 256 x 2B shorts: no sub-dword RMW, cheaper drain).
//  (3) Fragment-major Wlds (r11-proven conflict-free b128 reads).
//  (4) out (HBM) stores strictly AFTER the flag stores (off critical path;
//      r10/r11 regression source).
// Ordering: wave0's vmcnt(0) drains wave0's h stores (the only h stores)
// before its flag-replica stores -> flag implies h visible. Overwrite safety
// unchanged (ping-pong + all-flags>=t gate).

__global__ __launch_bounds__(256) void k_persist(const ushort* __restrict__ Whb,
                                                 const float* __restrict__ Axc,
                                                 ushort* __restrict__ hb0,
                                                 ushort* __restrict__ hb1,
                                                 float* __restrict__ out,
                                                 uint32_t* __restrict__ flg2,
                                                 float* __restrict__ cst,
                                                 int t0, int TC) {
  __shared__ ushort Wlds[8192 * 8];     // 128 KB fragment-major
  __shared__ float red[4][16][65];      // K-split reduce
  __shared__ ushort h_sh[16][16];       // packed publish tile

  const int bid = blockIdx.x;
  const int team = bid >> 6, hg = bid & 63;
  const int tid = threadIdx.x, w = tid >> 6, l = tid & 63;
  const int fr = l & 15, fq = l >> 4;

  // ---- stage Wh slice fragment-major: f = ((kc*4)+bj)*64 + lane ----
  for (int it = 0; it < 32; ++it) {
    int f = it * 256 + tid;
    int fl = f & 63, bj = (f >> 6) & 3, kc = f >> 8;
    bf16x8 v = *(const bf16x8*)(Whb + (size_t)(hg * 64 + bj * 16 + (fl & 15)) * 1024
                                + kc * 32 + (fl >> 4) * 8);
    *(bf16x8*)&Wlds[(size_t)f * 8] = v;
  }
  __syncthreads();

  const int eb = tid >> 4, ej = tid & 15;  // epilogue: batch-in-team, hcol-in-group
  const int hidx_self = (team * 16 + eb) * 1024 + hg * 16 + ej;
  float creg = cst[hidx_self];

  const size_t roff = (size_t)(team * 16 + fr) * 1024 + w * 256 + fq * 8;
  const uint32_t* fladdr = flg2 + bid * 64 + l;   // PRIVATE: lane l <- producer l

  for (int tt = 0; tt < TC; ++tt) {
    const int t = t0 + tt;
    const ushort* hb_r = (t & 1) ? hb0 : hb1;   // h_{t-1} in buf[(t-1)&1]
    ushort*       hb_w = (t & 1) ? hb1 : hb0;   // h_t -> buf[t&1]

    // ---- Ax prefetch (h-independent; overlaps poll) ----
    const float* axp = Axc + ((size_t)tt * 64 + team * 16 + eb) * NG + hg * 64;
    float ax0 = axp[ej], ax1 = axp[16 + ej], ax2 = axp[32 + ej], ax3 = axp[48 + ej];

    // ---- poll private 64-flag array until all >= t ----
    if (t > 0) {
      int guard = 0;
      while (true) {
        uint32_t v = ld_dword_dev(fladdr);
        WAITV(0);
        if (__all((int)(v >= (uint32_t)t))) break;
        if (++guard > (1 << 15)) break;   // bug guard: fail visibly, don't hang
      }
    }

    // ---- bulk read h_{t-1} + counted-vmcnt per-slice MFMA pipeline ----
    const ushort* aBt = hb_r + roff;
    u32x4 hv[8];
    f32x4 acc[4] = {};
#pragma unroll
    for (int ks = 0; ks < 8; ++ks) hv[ks] = ld_x4_dev(aBt + ks * 32);
#define SLICE(ks) do {                                                        \
      bf16x8 a_ = __builtin_bit_cast(bf16x8, hv[ks]);                         \
      _Pragma("unroll")                                                       \
      for (int bj = 0; bj < 4; ++bj) {                                        \
        bf16x8 b_ = *(const bf16x8*)&Wlds[(size_t)(((w * 8 + (ks)) * 4 + bj) * 64 + l) * 8]; \
        acc[bj] = mfma_bf16(a_, b_, acc[bj]);                                 \
      }                                                                       \
    } while (0)
    WAITV(7); SLICE(0);
    WAITV(6); SLICE(1);
    WAITV(5); SLICE(2);
    WAITV(4); SLICE(3);
    WAITV(3); SLICE(4);
    WAITV(2); SLICE(5);
    WAITV(1); SLICE(6);
    WAITV(0); SLICE(7);
#undef SLICE

#pragma unroll
    for (int bj = 0; bj < 4; ++bj)
#pragma unroll
      for (int jr = 0; jr < 4; ++jr)
        red[w][fq * 4 + jr][bj * 16 + fr] = acc[bj][jr];
    __syncthreads();

    // ---- epilogue: one (batch, hcol) per thread ----
    float ai_ = 0.f, af_ = 0.f, ao_ = 0.f, ag_ = 0.f;
#pragma unroll
    for (int ww = 0; ww < 4; ++ww) {
      ai_ += red[ww][eb][ej];
      af_ += red[ww][eb][16 + ej];
      ao_ += red[ww][eb][32 + ej];
      ag_ += red[ww][eb][48 + ej];
    }
    ai_ += ax0; af_ += ax1; ao_ += ax2; ag_ += ax3;

    float ig = sigm_f(ai_);
    float fg = sigm_f(af_);
    float og = sigm_f(ao_);
    float gg = tanh_f(ag_);
    creg = creg * fg + ig * gg;
    float h = og * tanh_f(creg);
    h_sh[eb][ej] = f2bf(h);
    __syncthreads();   // pack complete + red[] reuse guard

    // ---- publish (wave0 only): 32 x 16B h stores -> drain -> 64 flags ----
    if (w == 0) {
      if (l < 32) {
        int prow = l >> 1, phalf = (l & 1) * 8;
        u32x4 pv = *(const u32x4*)&h_sh[prow][phalf];
        st_x4_dev(hb_w + (size_t)(team * 16 + prow) * 1024 + hg * 16 + phalf, pv);
      }
      asm volatile("s_waitcnt vmcnt(0)" ::: "memory");   // h visible at L3
      __builtin_amdgcn_sched_barrier(0);
      // replicate flag into each consumer's private slot (fire-and-forget)
      st_dword_dev(flg2 + (team * 64 + l) * 64 + hg, (uint32_t)(t + 1));
    }

    // ---- out (HBM) stores strictly after flags ----
    out[(size_t)t * 65536 + hidx_self] = h;
    if (t == SEQ - 1) out[(size_t)SEQ * 65536 + hidx_self] = h;
  }

  cst[hidx_self] = creg;
}

// ---------------- fallback per-step kernel (ws too small for any Ax chunk) ----------------

__global__ __launch_bounds__(256) void k_step(int t,
                                              const ushort* __restrict__ Xb,
                                              const ushort* __restrict__ Wxb,
                                              const ushort* __restrict__ Whb,
                                              const float* __restrict__ bp,
                                              const ushort* __restrict__ hprev,
                                              ushort* __restrict__ hnext,
                                              float* __restrict__ cst,
                                              float* __restrict__ out) {
  __shared__ float red[4][16][65];
  const int bidx = blockIdx.x;
  const int cg = bidx & 63, mb = bidx >> 6;
  const int b0 = mb * 16, pcol = cg * 64;
  const int tid = threadIdx.x, w = tid >> 6, l = tid & 63;
  const int fr = l & 15, fk8 = (l >> 4) * 8, fq = l >> 4;

  f32x4 acc[4] = {};

  const ushort* aSrc;
  const ushort* bMat;
  int kbase;
  if (w < 2) { aSrc = Xb + (size_t)(t * 64 + b0 + fr) * 1024 + w * 512 + fk8; bMat = Wxb; kbase = w * 512; }
  else       { aSrc = hprev + (size_t)(b0 + fr) * 1024 + (w - 2) * 512 + fk8; bMat = Whb; kbase = (w - 2) * 512; }
  const ushort* bRow = bMat + (size_t)(pcol + fr) * 1024 + kbase + fk8;

#pragma unroll
  for (int ks = 0; ks < 16; ks++) {
    int kk = ks * 32;
    bf16x8 a = *(const bf16x8*)(aSrc + kk);
#pragma unroll
    for (int bj = 0; bj < 4; bj++) {
      bf16x8 bfv = *(const bf16x8*)(bRow + (size_t)bj * 16 * 1024 + kk);
      acc[bj] = mfma_bf16(a, bfv, acc[bj]);
    }
  }

#pragma unroll
  for (int bj = 0; bj < 4; bj++)
#pragma unroll
    for (int jr = 0; jr < 4; jr++)
      red[w][fq * 4 + jr][bj * 16 + fr] = acc[bj][jr];
  __syncthreads();

  const int b = tid >> 4, j = tid & 15;
  float ai_ = 0.f, af_ = 0.f, ao_ = 0.f, ag_ = 0.f;
#pragma unroll
  for (int ww = 0; ww < 4; ww++) {
    ai_ += red[ww][b][j];
    af_ += red[ww][b][16 + j];
    ao_ += red[ww][b][32 + j];
    ag_ += red[ww][b][48 + j];
  }
  ai_ += bp[pcol + j]; af_ += bp[pcol + 16 + j]; ao_ += bp[pcol + 32 + j]; ag_ += bp[pcol + 48 + j];

  float ig = sigm_f(ai_);
  float fg = sigm_f(af_);
  float og = sigm_f(ao_);
  float gg = tanh_f(ag_);
  int hidx = (b0 + b) * 1024 + cg * 16 + j;
  float cn = cst[hidx] * fg + ig * gg;
  cst[hidx] = cn;
  float h = og * tanh_f(cn);
  out[(size_t)t * 65536 + hidx] = h;
  hnext[hidx] = f2bf(h);
  if (t == SEQ - 1) out[(size_t)SEQ * 65536 + hidx] = h;
}

// ---------------- host ----------------

extern "C" void kernel_launch(void* const* d_in, const int* in_sizes, int n_in,
                              void* d_out, int out_size, void* d_ws, size_t ws_size,
                              hipStream_t stream) {
  const float* X    = (const float*)d_in[0];
  const float* W    = (const float*)d_in[1];
  const float* bvec = (const float*)d_in[2];
  float* out = (float*)d_out;
  char* ws = (char*)d_ws;

  size_t off = 0;
  auto alloc = [&](size_t bytes) -> char* {
    char* p = ws + off;
    off += (bytes + 255) & ~(size_t)255;
    return p;
  };
  ushort*   Xb   = (ushort*)alloc((size_t)SEQ * BATCH * NIN * 2);
  ushort*   Wxb  = (ushort*)alloc((size_t)NG * NIN * 2);
  ushort*   Whb  = (ushort*)alloc((size_t)NG * NHID * 2);
  float*    bp   = (float*)alloc((size_t)NG * 4);
  ushort*   hb0  = (ushort*)alloc((size_t)BATCH * NHID * 2);
  ushort*   hb1  = (ushort*)alloc((size_t)BATCH * NHID * 2);
  float*    cst  = (float*)alloc((size_t)BATCH * NHID * 4);
  uint32_t* flg2 = (uint32_t*)alloc(256 * 64 * 4);   // replicated flags
  size_t base_need = off;

  if (ws_size < base_need) return;

  // largest chunk length TC (steps) whose f32 Ax chunk fits the remaining ws
  size_t avail = ws_size - base_need;
  int TC = 0;
  for (int tc = 512; tc >= 16; tc >>= 1) {
    if ((size_t)tc * 64 * NG * 4 <= avail) { TC = tc; break; }
  }
  float* Axc = (float*)(ws + base_need);  // base_need is 256B-aligned

  k_convert_x<<<(SEQ * BATCH * NIN / 4 + 255) / 256, 256, 0, stream>>>(X, Xb, SEQ * BATCH * NIN / 4);
  k_convert_w<<<NG, 256, 0, stream>>>(W, bvec, Wxb, Whb, bp);
  k_zero<<<BATCH * NHID / 256, 256, 0, stream>>>(hb0, hb1, cst, flg2);

  if (TC > 0) {
    for (int c = 0; c < SEQ / TC; ++c) {
      k_gemm1<<<dim3(TC * 64 / 128, NG / 128), 256, 0, stream>>>(
          Xb + (size_t)c * TC * 64 * 1024, Wxb, bp, Axc);
      k_persist<<<256, 256, 0, stream>>>(Whb, Axc, hb0, hb1, out, flg2, cst, c * TC, TC);
    }
  } else {
    for (int t = 0; t < SEQ; t++) {
      const ushort* hp = (t & 1) ? hb1 : hb0;
      ushort*       hn = (t & 1) ? hb0 : hb1;
      k_step<<<256, 256, 0, stream>>>(t, Xb, Wxb, Whb, bp, hp, hn, cst, out);
    }
  }
}

// Round 13
// 2275.191 us; speedup vs baseline: 2.2312x; 1.0093x over previous
//
#include <hip/hip_runtime.h>
#include <hip/hip_bf16.h>
#include <stdint.h>
#include <stddef.h>

#define SEQ   512
#define BATCH 64
#define NIN   1024
#define NHID  1024
#define NG    4096   // 4*NHID

typedef __attribute__((ext_vector_type(8))) short bf16x8;
typedef __attribute__((ext_vector_type(4))) float f32x4;
typedef __attribute__((ext_vector_type(4))) uint32_t u32x4;

static __device__ __forceinline__ ushort f2bf(float f) {
  uint32_t u = __builtin_bit_cast(uint32_t, f);
  uint32_t lsb = (u >> 16) & 1u;
  u += 0x7fffu + lsb;           // round-to-nearest-even
  return (ushort)(u >> 16);
}

static __device__ __forceinline__ f32x4 mfma_bf16(bf16x8 a, bf16x8 b, f32x4 c) {
  return __builtin_amdgcn_mfma_f32_16x16x32_bf16(a, b, c, 0, 0, 0);
}

static __device__ __forceinline__ void lds_load16(const ushort* g, ushort* l) {
  __builtin_amdgcn_global_load_lds(
      (const __attribute__((address_space(1))) void*)g,
      (__attribute__((address_space(3))) void*)l, 16, 0, 0);
}

// ---- exchange primitives: DEVICE scope (sc1) -- proven correct in r10 ----
static __device__ __forceinline__ void st_short_dev(ushort* p, uint32_t v) {
  asm volatile("global_store_short %0, %1, off sc1" :: "v"(p), "v"(v) : "memory");
}
static __device__ __forceinline__ void st_dword_dev(uint32_t* p, uint32_t v) {
  asm volatile("global_store_dword %0, %1, off sc1" :: "v"(p), "v"(v) : "memory");
}
static __device__ __forceinline__ void st_x4_dev(ushort* p, u32x4 v) {
  asm volatile("global_store_dwordx4 %0, %1, off sc1" :: "v"(p), "v"(v) : "memory");
}
static __device__ __forceinline__ uint32_t ld_dword_dev(const uint32_t* p) {
  uint32_t v;
  asm volatile("global_load_dword %0, %1, off sc1" : "=v"(v) : "v"(p) : "memory");
  return v;
}
static __device__ __forceinline__ u32x4 ld_x4_dev(const ushort* p) {
  u32x4 v;
  asm volatile("global_load_dwordx4 %0, %1, off sc1" : "=v"(v) : "v"(p) : "memory");
  return v;
}

#define WAITV(n) do { asm volatile("s_waitcnt vmcnt(" #n ")" ::: "memory"); \
                      __builtin_amdgcn_sched_barrier(0); } while (0)

// fast transcendentals
static __device__ __forceinline__ float sigm_f(float x) {
  return __builtin_amdgcn_rcpf(1.f + __expf(-x));
}
static __device__ __forceinline__ float tanh_f(float x) {
  return 1.f - 2.f * __builtin_amdgcn_rcpf(__expf(2.f * x) + 1.f);
}

// ---------------- converts ----------------

__global__ __launch_bounds__(256) void k_convert_x(const float* __restrict__ X,
                                                   ushort* __restrict__ Xb, int n4) {
  int i = blockIdx.x * 256 + threadIdx.x;
  if (i < n4) {
    float4 v = ((const float4*)X)[i];
    ushort4 o;
    o.x = f2bf(v.x); o.y = f2bf(v.y); o.z = f2bf(v.z); o.w = f2bf(v.w);
    ((ushort4*)Xb)[i] = o;
  }
}

// permuted row order: p = cg*64 + g*16 + j  <->  r = g*1024 + cg*16 + j
__global__ __launch_bounds__(256) void k_convert_w(const float* __restrict__ W,
                                                   const float* __restrict__ bvec,
                                                   ushort* __restrict__ Wxb,
                                                   ushort* __restrict__ Whb,
                                                   float* __restrict__ bp) {
  int p = blockIdx.x;
  int cg = p >> 6, g = (p >> 4) & 3, j = p & 15;
  int r = g * 1024 + cg * 16 + j;
  const float* src = W + (size_t)r * 2048;
  for (int k4 = threadIdx.x; k4 < 512; k4 += 256) {
    float4 v = ((const float4*)src)[k4];
    ushort4 o;
    o.x = f2bf(v.x); o.y = f2bf(v.y); o.z = f2bf(v.z); o.w = f2bf(v.w);
    if (k4 < 256) ((ushort4*)(Wxb + (size_t)p * 1024))[k4] = o;
    else          ((ushort4*)(Whb + (size_t)p * 1024))[k4 - 256] = o;
  }
  if (threadIdx.x == 0) bp[p] = bvec[r];
}

// zero h ping-pong, c-state, replicated flags (16384 dwords)
__global__ __launch_bounds__(256) void k_zero(ushort* __restrict__ hb0,
                                              ushort* __restrict__ hb1,
                                              float* __restrict__ cst,
                                              uint32_t* __restrict__ flg2) {
  int i = blockIdx.x * 256 + threadIdx.x;  // 65536 total
  st_short_dev(hb0 + i, 0u);
  st_short_dev(hb1 + i, 0u);
  cst[i] = 0.f;
  if (i < 256 * 64) st_dword_dev(flg2 + i, 0u);
}

// ---------------- GEMM1 chunk (unchanged, proven) ----------------

__global__ __launch_bounds__(256) void k_gemm1(const ushort* __restrict__ Xbc,
                                               const ushort* __restrict__ Wxb,
                                               const float* __restrict__ bp,
                                               float* __restrict__ Axc) {
  __shared__ ushort As[128 * 32];
  __shared__ ushort Bs[128 * 32];
  const int m0 = blockIdx.x * 128;
  const int n0 = blockIdx.y * 128;
  const int tid = threadIdx.x;
  const int w = tid >> 6, l = tid & 63;
  const int wr = w >> 1, wc = w & 1;
  const int lr = l >> 2;
  const int lc = (l & 3) * 8;
  const int fr = l & 15, fk8 = (l >> 4) * 8, fq = l >> 4;

  f32x4 acc[4][4] = {};

  for (int kb = 0; kb < 1024; kb += 32) {
    lds_load16(Xbc + (size_t)(m0 + w * 16 + lr) * 1024 + kb + lc,       &As[w * 512]);
    lds_load16(Xbc + (size_t)(m0 + (w + 4) * 16 + lr) * 1024 + kb + lc, &As[(w + 4) * 512]);
    lds_load16(Wxb + (size_t)(n0 + w * 16 + lr) * 1024 + kb + lc,       &Bs[w * 512]);
    lds_load16(Wxb + (size_t)(n0 + (w + 4) * 16 + lr) * 1024 + kb + lc, &Bs[(w + 4) * 512]);
    __syncthreads();
    bf16x8 af[4], bfr[4];
#pragma unroll
    for (int i = 0; i < 4; i++) af[i]  = *(const bf16x8*)&As[(wr * 64 + i * 16 + fr) * 32 + fk8];
#pragma unroll
    for (int i = 0; i < 4; i++) bfr[i] = *(const bf16x8*)&Bs[(wc * 64 + i * 16 + fr) * 32 + fk8];
#pragma unroll
    for (int i = 0; i < 4; i++)
#pragma unroll
      for (int jj = 0; jj < 4; jj++)
        acc[i][jj] = mfma_bf16(af[i], bfr[jj], acc[i][jj]);
    __syncthreads();
  }

#pragma unroll
  for (int jj = 0; jj < 4; jj++) {
    int gc = n0 + wc * 64 + jj * 16 + fr;
    float bb = bp[gc];
#pragma unroll
    for (int i = 0; i < 4; i++) {
      int grb = m0 + wr * 64 + i * 16 + fq * 4;
#pragma unroll
      for (int jr = 0; jr < 4; jr++)
        Axc[(size_t)(grb + jr) * NG + gc] = acc[i][jj][jr] + bb;
    }
  }
}

// ---------------- persistent recurrence chunk ----------------
// r12 champion + per-wave fan-in-16 polling + 2-deep poll pipeline.
// Structure: 256 blocks = 4 teams x 64 hg; block = 16 batches x 64 gate cols;
// 4 waves split K. Wave w's K-span [w*256,+256) touches h cols produced by
// EXACTLY 16 blocks (hg = w*16..w*16+15) -> wave w polls only those 16 flags
// (lanes 4x-redundant on (l&15)) and starts its h-read+MFMA as soon as ITS
// producers land -- compute overlaps other producers' publishes.
// Overwrite safety: union of the 4 per-wave gates = all-64 gate; the pack
// __syncthreads before any buf write enforces the union (ping-pong proof
// unchanged from r7/r12). Replicated private flags + packed 16B publish +
// fragment-major Wlds + out-after-flag all carried from r12.

__global__ __launch_bounds__(256) void k_persist(const ushort* __restrict__ Whb,
                                                 const float* __restrict__ Axc,
                                                 ushort* __restrict__ hb0,
                                                 ushort* __restrict__ hb1,
                                                 float* __restrict__ out,
                                                 uint32_t* __restrict__ flg2,
                                                 float* __restrict__ cst,
                                                 int t0, int TC) {
  __shared__ ushort Wlds[8192 * 8];     // 128 KB fragment-major
  __shared__ float red[4][16][65];      // K-split reduce
  __shared__ ushort h_sh[16][16];       // packed publish tile

  const int bid = blockIdx.x;
  const int team = bid >> 6, hg = bid & 63;
  const int tid = threadIdx.x, w = tid >> 6, l = tid & 63;
  const int fr = l & 15, fq = l >> 4;

  // ---- stage Wh slice fragment-major: f = ((kc*4)+bj)*64 + lane ----
  for (int it = 0; it < 32; ++it) {
    int f = it * 256 + tid;
    int fl = f & 63, bj = (f >> 6) & 3, kc = f >> 8;
    bf16x8 v = *(const bf16x8*)(Whb + (size_t)(hg * 64 + bj * 16 + (fl & 15)) * 1024
                                + kc * 32 + (fl >> 4) * 8);
    *(bf16x8*)&Wlds[(size_t)f * 8] = v;
  }
  __syncthreads();

  const int eb = tid >> 4, ej = tid & 15;  // epilogue: batch-in-team, hcol-in-group
  const int hidx_self = (team * 16 + eb) * 1024 + hg * 16 + ej;
  float creg = cst[hidx_self];

  const size_t roff = (size_t)(team * 16 + fr) * 1024 + w * 256 + fq * 8;
  // fan-in-16: wave w polls ONLY its 16 producers (hg = w*16 + (l&15))
  const uint32_t* fladdr = flg2 + bid * 64 + w * 16 + (l & 15);

  for (int tt = 0; tt < TC; ++tt) {
    const int t = t0 + tt;
    const ushort* hb_r = (t & 1) ? hb0 : hb1;   // h_{t-1} in buf[(t-1)&1]
    ushort*       hb_w = (t & 1) ? hb1 : hb0;   // h_t -> buf[t&1]

    // ---- Ax prefetch (h-independent; overlaps poll) ----
    const float* axp = Axc + ((size_t)tt * 64 + team * 16 + eb) * NG + hg * 64;
    float ax0 = axp[ej], ax1 = axp[16 + ej], ax2 = axp[32 + ej], ax3 = axp[48 + ej];

    // ---- per-wave 2-deep pipelined poll of 16 producer flags ----
    if (t > 0) {
      int guard = 0;
      while (true) {
        uint32_t v0 = ld_dword_dev(fladdr);
        uint32_t v1 = ld_dword_dev(fladdr);
        asm volatile("s_waitcnt vmcnt(1)" ::: "memory");
        __builtin_amdgcn_sched_barrier(0);
        bool ok0 = __all((int)(v0 >= (uint32_t)t));
        asm volatile("s_waitcnt vmcnt(0)" ::: "memory");
        __builtin_amdgcn_sched_barrier(0);
        if (ok0) break;
        if (__all((int)(v1 >= (uint32_t)t))) break;
        if (++guard > (1 << 15)) break;   // bug guard: fail visibly, don't hang
      }
    }

    // ---- bulk read h_{t-1} (this wave's K-span) + counted-vmcnt pipeline ----
    const ushort* aBt = hb_r + roff;
    u32x4 hv[8];
    f32x4 acc[4] = {};
#pragma unroll
    for (int ks = 0; ks < 8; ++ks) hv[ks] = ld_x4_dev(aBt + ks * 32);
#define SLICE(ks) do {                                                        \
      bf16x8 a_ = __builtin_bit_cast(bf16x8, hv[ks]);                         \
      _Pragma("unroll")                                                       \
      for (int bj = 0; bj < 4; ++bj) {                                        \
        bf16x8 b_ = *(const bf16x8*)&Wlds[(size_t)(((w * 8 + (ks)) * 4 + bj) * 64 + l) * 8]; \
        acc[bj] = mfma_bf16(a_, b_, acc[bj]);                                 \
      }                                                                       \
    } while (0)
    WAITV(7); SLICE(0);
    WAITV(6); SLICE(1);
    WAITV(5); SLICE(2);
    WAITV(4); SLICE(3);
    WAITV(3); SLICE(4);
    WAITV(2); SLICE(5);
    WAITV(1); SLICE(6);
    WAITV(0); SLICE(7);
#undef SLICE

#pragma unroll
    for (int bj = 0; bj < 4; ++bj)
#pragma unroll
      for (int jr = 0; jr < 4; ++jr)
        red[w][fq * 4 + jr][bj * 16 + fr] = acc[bj][jr];
    __syncthreads();

    // ---- epilogue: one (batch, hcol) per thread ----
    float ai_ = 0.f, af_ = 0.f, ao_ = 0.f, ag_ = 0.f;
#pragma unroll
    for (int ww = 0; ww < 4; ++ww) {
      ai_ += red[ww][eb][ej];
      af_ += red[ww][eb][16 + ej];
      ao_ += red[ww][eb][32 + ej];
      ag_ += red[ww][eb][48 + ej];
    }
    ai_ += ax0; af_ += ax1; ao_ += ax2; ag_ += ax3;

    float ig = sigm_f(ai_);
    float fg = sigm_f(af_);
    float og = sigm_f(ao_);
    float gg = tanh_f(ag_);
    creg = creg * fg + ig * gg;
    float h = og * tanh_f(creg);
    h_sh[eb][ej] = f2bf(h);
    __syncthreads();   // pack complete + red[] reuse guard + union-of-gates

    // ---- publish (wave0 only): 32 x 16B h stores -> drain -> 64 flags ----
    if (w == 0) {
      if (l < 32) {
        int prow = l >> 1, phalf = (l & 1) * 8;
        u32x4 pv = *(const u32x4*)&h_sh[prow][phalf];
        st_x4_dev(hb_w + (size_t)(team * 16 + prow) * 1024 + hg * 16 + phalf, pv);
      }
      asm volatile("s_waitcnt vmcnt(0)" ::: "memory");   // h visible at L3
      __builtin_amdgcn_sched_barrier(0);
      // replicate flag into each consumer's private slot (fire-and-forget)
      st_dword_dev(flg2 + (team * 64 + l) * 64 + hg, (uint32_t)(t + 1));
    }

    // ---- out (HBM) stores strictly after flags ----
    out[(size_t)t * 65536 + hidx_self] = h;
    if (t == SEQ - 1) out[(size_t)SEQ * 65536 + hidx_self] = h;
  }

  cst[hidx_self] = creg;
}

// ---------------- fallback per-step kernel (ws too small for any Ax chunk) ----------------

__global__ __launch_bounds__(256) void k_step(int t,
                                              const ushort* __restrict__ Xb,
                                              const ushort* __restrict__ Wxb,
                                              const ushort* __restrict__ Whb,
                                              const float* __restrict__ bp,
                                              const ushort* __restrict__ hprev,
                                              ushort* __restrict__ hnext,
                                              float* __restrict__ cst,
                                              float* __restrict__ out) {
  __shared__ float red[4][16][65];
  const int bidx = blockIdx.x;
  const int cg = bidx & 63, mb = bidx >> 6;
  const int b0 = mb * 16, pcol = cg * 64;
  const int tid = threadIdx.x, w = tid >> 6, l = tid & 63;
  const int fr = l & 15, fk8 = (l >> 4) * 8, fq = l >> 4;

  f32x4 acc[4] = {};

  const ushort* aSrc;
  const ushort* bMat;
  int kbase;
  if (w < 2) { aSrc = Xb + (size_t)(t * 64 + b0 + fr) * 1024 + w * 512 + fk8; bMat = Wxb; kbase = w * 512; }
  else       { aSrc = hprev + (size_t)(b0 + fr) * 1024 + (w - 2) * 512 + fk8; bMat = Whb; kbase = (w - 2) * 512; }
  const ushort* bRow = bMat + (size_t)(pcol + fr) * 1024 + kbase + fk8;

#pragma unroll
  for (int ks = 0; ks < 16; ks++) {
    int kk = ks * 32;
    bf16x8 a = *(const bf16x8*)(aSrc + kk);
#pragma unroll
    for (int bj = 0; bj < 4; bj++) {
      bf16x8 bfv = *(const bf16x8*)(bRow + (size_t)bj * 16 * 1024 + kk);
      acc[bj] = mfma_bf16(a, bfv, acc[bj]);
    }
  }

#pragma unroll
  for (int bj = 0; bj < 4; bj++)
#pragma unroll
    for (int jr = 0; jr < 4; jr++)
      red[w][fq * 4 + jr][bj * 16 + fr] = acc[bj][jr];
  __syncthreads();

  const int b = tid >> 4, j = tid & 15;
  float ai_ = 0.f, af_ = 0.f, ao_ = 0.f, ag_ = 0.f;
#pragma unroll
  for (int ww = 0; ww < 4; ww++) {
    ai_ += red[ww][b][j];
    af_ += red[ww][b][16 + j];
    ao_ += red[ww][b][32 + j];
    ag_ += red[ww][b][48 + j];
  }
  ai_ += bp[pcol + j]; af_ += bp[pcol + 16 + j]; ao_ += bp[pcol + 32 + j]; ag_ += bp[pcol + 48 + j];

  float ig = sigm_f(ai_);
  float fg = sigm_f(af_);
  float og = sigm_f(ao_);
  float gg = tanh_f(ag_);
  int hidx = (b0 + b) * 1024 + cg * 16 + j;
  float cn = cst[hidx] * fg + ig * gg;
  cst[hidx] = cn;
  float h = og * tanh_f(cn);
  out[(size_t)t * 65536 + hidx] = h;
  hnext[hidx] = f2bf(h);
  if (t == SEQ - 1) out[(size_t)SEQ * 65536 + hidx] = h;
}

// ---------------- host ----------------

extern "C" void kernel_launch(void* const* d_in, const int* in_sizes, int n_in,
                              void* d_out, int out_size, void* d_ws, size_t ws_size,
                              hipStream_t stream) {
  const float* X    = (const float*)d_in[0];
  const float* W    = (const float*)d_in[1];
  const float* bvec = (const float*)d_in[2];
  float* out = (float*)d_out;
  char* ws = (char*)d_ws;

  size_t off = 0;
  auto alloc = [&](size_t bytes) -> char* {
    char* p = ws + off;
    off += (bytes + 255) & ~(size_t)255;
    return p;
  };
  ushort*   Xb   = (ushort*)alloc((size_t)SEQ * BATCH * NIN * 2);
  ushort*   Wxb  = (ushort*)alloc((size_t)NG * NIN * 2);
  ushort*   Whb  = (ushort*)alloc((size_t)NG * NHID * 2);
  float*    bp   = (float*)alloc((size_t)NG * 4);
  ushort*   hb0  = (ushort*)alloc((size_t)BATCH * NHID * 2);
  ushort*   hb1  = (ushort*)alloc((size_t)BATCH * NHID * 2);
  float*    cst  = (float*)alloc((size_t)BATCH * NHID * 4);
  uint32_t* flg2 = (uint32_t*)alloc(256 * 64 * 4);   // replicated flags
  size_t base_need = off;

  if (ws_size < base_need) return;

  // largest chunk length TC (steps) whose f32 Ax chunk fits the remaining ws
  size_t avail = ws_size - base_need;
  int TC = 0;
  for (int tc = 512; tc >= 16; tc >>= 1) {
    if ((size_t)tc * 64 * NG * 4 <= avail) { TC = tc; break; }
  }
  float* Axc = (float*)(ws + base_need);  // base_need is 256B-aligned

  k_convert_x<<<(SEQ * BATCH * NIN / 4 + 255) / 256, 256, 0, stream>>>(X, Xb, SEQ * BATCH * NIN / 4);
  k_convert_w<<<NG, 256, 0, stream>>>(W, bvec, Wxb, Whb, bp);
  k_zero<<<BATCH * NHID / 256, 256, 0, stream>>>(hb0, hb1, cst, flg2);

  if (TC > 0) {
    for (int c = 0; c < SEQ / TC; ++c) {
      k_gemm1<<<dim3(TC * 64 / 128, NG / 128), 256, 0, stream>>>(
          Xb + (size_t)c * TC * 64 * 1024, Wxb, bp, Axc);
      k_persist<<<256, 256, 0, stream>>>(Whb, Axc, hb0, hb1, out, flg2, cst, c * TC, TC);
    }
  } else {
    for (int t = 0; t < SEQ; t++) {
      const ushort* hp = (t & 1) ? hb1 : hb0;
      ushort*       hn = (t & 1) ? hb0 : hb1;
      k_step<<<256, 256, 0, stream>>>(t, Xb, Wxb, Whb, bp, hp, hn, cst, out);
    }
  }
}